// Round 12
// baseline (542.691 us; speedup 1.0000x reference)
//
#include <hip/hip_runtime.h>
#include <hip/hip_fp16.h>
#include <math.h>

#define N_NODES 100000
#define N_EDGES 1600000
#define IN_FEATS 128
#define H_FEATS 64
#define SCAN_BLOCKS 391   // ceil(100000/256)
#define NWIN 8
#define WIN_SZ 12500      // N_NODES / NWIN exactly

typedef _Float16 f16x8 __attribute__((ext_vector_type(8)));
typedef float f32x4 __attribute__((ext_vector_type(4)));

// ---------------- windowed degree histogram: degw[n][w], w = src/WIN_SZ ----------------
__global__ __launch_bounds__(256) void hist2_kernel(const int* __restrict__ src,
                                                    const int* __restrict__ dst,
                                                    int* __restrict__ degw) {
    int tid = blockIdx.x * 256 + threadIdx.x;
    int stride = gridDim.x * 256;
    for (int e = tid; e < N_EDGES; e += stride) {
        int d = dst[e];
        int w = src[e] / WIN_SZ;
        atomicAdd(&degw[d * NWIN + w], 1);
    }
}

// degi[n] = sum_w degw[n][w];  dinv[n] = rsqrt(max(deg,1))
__global__ __launch_bounds__(256) void sumdinv_kernel(const int* __restrict__ degw,
                                                      int* __restrict__ degi,
                                                      float* __restrict__ dinv) {
    int n = blockIdx.x * 256 + threadIdx.x;
    if (n >= N_NODES) return;
    int s = 0;
    #pragma unroll
    for (int w = 0; w < NWIN; ++w) s += degw[n * NWIN + w];
    degi[n] = s;
    dinv[n] = rsqrtf(fmaxf((float)s, 1.0f));
}

// ---------------- 3-kernel exclusive scan of degi -> rowp ----------------
__global__ __launch_bounds__(256) void scan1_kernel(const int* __restrict__ degi,
                                                    int* __restrict__ rowp,
                                                    int* __restrict__ bsums) {
    __shared__ int tmp[256];
    int i = blockIdx.x * 256 + threadIdx.x;
    int v = (i < N_NODES) ? degi[i] : 0;
    tmp[threadIdx.x] = v;
    __syncthreads();
    #pragma unroll
    for (int off = 1; off < 256; off <<= 1) {
        int t = (threadIdx.x >= off) ? tmp[threadIdx.x - off] : 0;
        __syncthreads();
        tmp[threadIdx.x] += t;
        __syncthreads();
    }
    if (i < N_NODES) rowp[i] = tmp[threadIdx.x] - v;
    if (threadIdx.x == 255) bsums[blockIdx.x] = tmp[255];
}

__global__ __launch_bounds__(512) void scan2_kernel(int* __restrict__ bsums) {
    __shared__ int tmp[512];
    int t = threadIdx.x;
    int v = (t < SCAN_BLOCKS) ? bsums[t] : 0;
    tmp[t] = v;
    __syncthreads();
    #pragma unroll
    for (int off = 1; off < 512; off <<= 1) {
        int x = (t >= off) ? tmp[t - off] : 0;
        __syncthreads();
        tmp[t] += x;
        __syncthreads();
    }
    if (t < SCAN_BLOCKS) bsums[t] = tmp[t] - v;
}

__global__ __launch_bounds__(256) void scan3_kernel(int* __restrict__ rowp,
                                                    const int* __restrict__ bsums) {
    int i = blockIdx.x * 256 + threadIdx.x;
    if (i < N_NODES) rowp[i] += bsums[blockIdx.x];
    if (i == N_NODES) rowp[N_NODES] = N_EDGES;
}

// ---------------- rowpw[n][w] = rowp[n] + prefix_{w'<w} degw[n][w'] ----------------
__global__ __launch_bounds__(256) void rowpw_kernel(const int* __restrict__ rowp,
                                                    const int* __restrict__ degw,
                                                    int* __restrict__ rowpw) {
    int n = blockIdx.x * 256 + threadIdx.x;
    if (n >= N_NODES) return;
    int b = rowp[n];
    #pragma unroll
    for (int w = 0; w < NWIN; ++w) {
        rowpw[n * NWIN + w] = b;
        b += degw[n * NWIN + w];
    }
}

// ---------------- fill CSR slots, grouped by src-window within each row ----------------
__global__ __launch_bounds__(256) void fill_kernel(const int* __restrict__ src,
                                                   const int* __restrict__ dst,
                                                   const int* __restrict__ rowpw,
                                                   const float* __restrict__ dinv,
                                                   int* __restrict__ cursorw,
                                                   int2* __restrict__ epack) {
    int tid = blockIdx.x * 256 + threadIdx.x;
    int stride = gridDim.x * 256;
    for (int e = tid; e < N_EDGES; e += stride) {
        int d = dst[e];
        int s = src[e];
        int w = s / WIN_SZ;
        int slot = rowpw[d * NWIN + w] + atomicAdd(&cursorw[d * NWIN + w], 1);
        epack[slot] = make_int2(s, __float_as_int(dinv[s]));
    }
}

// ---------------- Bpack: Weff collapsed + fp16 + MFMA B-fragment order ----------------
// Fragment (s, nt): lane l, elem j holds B[k = 32s + (l>>4)*8 + j][n = nt*16 + (l&15)]
// where B[k][n] = Weff[q = k>>6][f = k&63][n] = sum_c thetas[c][q] * Wm1[c*64+f][n].
__global__ __launch_bounds__(256) void wpack_kernel(const float* __restrict__ thetas,
                                                    const float* __restrict__ Wm1,
                                                    __half* __restrict__ Bpack) {
    int u = blockIdx.x * 256 + threadIdx.x;   // 16384 total
    int j = u & 7, lane = (u >> 3) & 63, frag = u >> 9;
    int nt = frag & 3, s = frag >> 2;
    int k = 32 * s + ((lane >> 4) << 3) + j;
    int q = k >> 6, f = k & 63;
    int n = nt * 16 + (lane & 15);
    float acc = 0.f;
    #pragma unroll
    for (int c = 0; c < 3; ++c)
        acc = fmaf(thetas[c * 4 + q], Wm1[(c * 64 + f) * 64 + n], acc);
    Bpack[u] = __float2half(acc);
}

// ---------------- trunk: h = relu(relu(X@W1+b1)@W2+b2) -> half table L0h ----------------
__global__ __launch_bounds__(256) void trunk_kernel(
    const float* __restrict__ X, const float* __restrict__ W1, const float* __restrict__ b1,
    const float* __restrict__ W2, const float* __restrict__ b2, __half* __restrict__ H)
{
    __shared__ float stage[16][IN_FEATS];   // 8 KB = 512 float4
    __shared__ float part[4][16][64];       // 16 KB
    __shared__ float h1s[16][64];           // 4 KB
    int t = threadIdx.x;
    int wv = __builtin_amdgcn_readfirstlane(t >> 6);
    int lane = t & 63;
    float w1r[32], w2r[16];
    #pragma unroll
    for (int i = 0; i < 32; ++i) w1r[i] = W1[(wv * 32 + i) * 64 + lane];
    #pragma unroll
    for (int i = 0; i < 16; ++i) w2r[i] = W2[(wv * 16 + i) * 64 + lane];
    float b1v = b1[lane], b2v = b2[lane];
    int srow = t >> 5, sf4 = t & 31;
    float4* st4 = (float4*)stage;

    for (int batch = 0; batch < 4; ++batch) {
        int row0 = blockIdx.x * 64 + batch * 16;
        #pragma unroll
        for (int p = 0; p < 2; ++p) {
            int row = row0 + srow + 8 * p;
            if (row >= N_NODES) row = N_NODES - 1;
            st4[t + 256 * p] =
                ((const float4*)(X + (size_t)row * IN_FEATS))[sf4];
        }
        __syncthreads();
        float acc[16];
        #pragma unroll
        for (int r = 0; r < 16; ++r) {
            const float4* xb = (const float4*)&stage[r][wv * 32];   // uniform -> broadcast
            float a = 0.f, b = 0.f;
            #pragma unroll
            for (int i4 = 0; i4 < 8; i4 += 2) {
                float4 v0 = xb[i4], v1 = xb[i4 + 1];
                a = fmaf(v0.x, w1r[i4 * 4 + 0], a);
                a = fmaf(v0.y, w1r[i4 * 4 + 1], a);
                a = fmaf(v0.z, w1r[i4 * 4 + 2], a);
                a = fmaf(v0.w, w1r[i4 * 4 + 3], a);
                b = fmaf(v1.x, w1r[i4 * 4 + 4], b);
                b = fmaf(v1.y, w1r[i4 * 4 + 5], b);
                b = fmaf(v1.z, w1r[i4 * 4 + 6], b);
                b = fmaf(v1.w, w1r[i4 * 4 + 7], b);
            }
            acc[r] = a + b;
        }
        #pragma unroll
        for (int r = 0; r < 16; ++r) part[wv][r][lane] = acc[r];
        __syncthreads();
        #pragma unroll
        for (int rr = 0; rr < 4; ++rr) {
            int r = wv * 4 + rr;
            float y1 = part[0][r][lane] + part[1][r][lane] +
                       part[2][r][lane] + part[3][r][lane] + b1v;
            h1s[r][lane] = fmaxf(y1, 0.f);
        }
        __syncthreads();
        float acc2[16];
        #pragma unroll
        for (int r = 0; r < 16; ++r) {
            const float4* xb = (const float4*)&h1s[r][wv * 16];     // uniform -> broadcast
            float a = 0.f, b = 0.f;
            #pragma unroll
            for (int i4 = 0; i4 < 4; i4 += 2) {
                float4 v0 = xb[i4], v1 = xb[i4 + 1];
                a = fmaf(v0.x, w2r[i4 * 4 + 0], a);
                a = fmaf(v0.y, w2r[i4 * 4 + 1], a);
                a = fmaf(v0.z, w2r[i4 * 4 + 2], a);
                a = fmaf(v0.w, w2r[i4 * 4 + 3], a);
                b = fmaf(v1.x, w2r[i4 * 4 + 4], b);
                b = fmaf(v1.y, w2r[i4 * 4 + 5], b);
                b = fmaf(v1.z, w2r[i4 * 4 + 6], b);
                b = fmaf(v1.w, w2r[i4 * 4 + 7], b);
            }
            acc2[r] = a + b;
        }
        __syncthreads();
        #pragma unroll
        for (int r = 0; r < 16; ++r) part[wv][r][lane] = acc2[r];
        __syncthreads();
        #pragma unroll
        for (int rr = 0; rr < 4; ++rr) {
            int r = wv * 4 + rr;
            int row = row0 + r;
            float y2 = part[0][r][lane] + part[1][r][lane] +
                       part[2][r][lane] + part[3][r][lane] + b2v;
            if (row < N_NODES) H[(size_t)row * 64 + lane] = __float2half(fmaxf(y2, 0.f));
        }
        __syncthreads();
    }
}

// ---------------- gather pass (window-phased): Fnew = Fprev - dinv*sum w_e*Fprev[s_e]
// One wave owns 8 consecutive nodes with persistent acc[8]; outer loop over the
// 8 src-windows (rows are window-grouped by fill) -> whole grid sweeps the fp16
// table one 1.6MB window at a time -> window stays L2-resident, reads become
// L2 hits (latency down ~3x; gather is miss-concurrency x latency bound).
__global__ __launch_bounds__(256) void gather_kernel(
    const __half* __restrict__ Fprev, const int* __restrict__ rowp,
    const int* __restrict__ rowpw, const int2* __restrict__ epack,
    const float* __restrict__ dinv, __half* __restrict__ Fnew)
{
    int wv = __builtin_amdgcn_readfirstlane(threadIdx.x >> 6);
    int lane = threadIdx.x & 63;
    int base = (blockIdx.x * 4 + wv) * 8;   // 8 consecutive nodes, grid covers N exactly
    float acc[8] = {0.f, 0.f, 0.f, 0.f, 0.f, 0.f, 0.f, 0.f};
    for (int win = 0; win < NWIN; ++win) {
        #pragma unroll
        for (int u = 0; u < 8; ++u) {
            int n = base + u;
            int j = rowpw[n * NWIN + win];
            int jend = (win < NWIN - 1) ? rowpw[n * NWIN + win + 1] : rowp[n + 1];
            for (; j + 1 < jend; j += 2) {
                int2 ea = epack[j], eb = epack[j + 1];
                float va = __half2float(Fprev[(size_t)ea.x * 64 + lane]);
                float vb = __half2float(Fprev[(size_t)eb.x * 64 + lane]);
                acc[u] = fmaf(va, __int_as_float(ea.y), acc[u]);
                acc[u] = fmaf(vb, __int_as_float(eb.y), acc[u]);
            }
            if (j < jend) {
                int2 e = epack[j];
                acc[u] = fmaf(__half2float(Fprev[(size_t)e.x * 64 + lane]),
                              __int_as_float(e.y), acc[u]);
            }
        }
    }
    #pragma unroll
    for (int u = 0; u < 8; ++u) {
        int n = base + u;
        float self = __half2float(Fprev[(size_t)n * 64 + lane]);
        Fnew[(size_t)n * 64 + lane] = __float2half(self - acc[u] * dinv[n]);
    }
}

// ---------------- final (MFMA): out = relu(A@B + bm1) @ Wm2 + bm2 ----------------
// A[100000 x 256] fp16 = [L0|L1|L2|L3] column-blocked (Lh contiguous);
// B[256 x 64] fp16 pre-packed in fragment order (Bpack).
// D: col n = nt*16 + (l&15), row = row0 + (l>>4)*4 + reg   [m89 layout]
__global__ __launch_bounds__(256) void final_mfma_kernel(
    const __half* __restrict__ L0h, const __half* __restrict__ Bpack,
    const float* __restrict__ Wm2, const float* __restrict__ bm1,
    const float* __restrict__ bm2, float* __restrict__ out)
{
    const size_t NH = (size_t)N_NODES * 64;
    int t = threadIdx.x;
    int wv = t >> 6;
    int lane = t & 63;
    int gw = blockIdx.x * 4 + wv;          // 1564 waves

    // preload all 32 B fragments (128 VGPRs)
    const f16x8* bp = (const f16x8*)Bpack;
    f16x8 b[4][8];
    #pragma unroll
    for (int s = 0; s < 8; ++s)
        #pragma unroll
        for (int nt = 0; nt < 4; ++nt)
            b[nt][s] = bp[(s * 4 + nt) * 64 + lane];

    // per-lane head constants: n = nt*16 + (lane&15)
    float bm1v[4], w20[4], w21[4];
    #pragma unroll
    for (int nt = 0; nt < 4; ++nt) {
        int n = nt * 16 + (lane & 15);
        bm1v[nt] = bm1[n];
        w20[nt] = Wm2[n * 2 + 0];
        w21[nt] = Wm2[n * 2 + 1];
    }
    float bm20 = bm2[0], bm21 = bm2[1];

    for (int u = 0; u < 4; ++u) {
        int tile = gw * 4 + u;
        if (tile >= 6250) break;           // 6250 * 16 = 100000 exactly
        int row0 = tile * 16;
        const __half* abase = L0h + (size_t)(row0 + (lane & 15)) * 64 + ((lane >> 4) << 3);
        f16x8 a[8];
        #pragma unroll
        for (int s = 0; s < 8; ++s)
            a[s] = *(const f16x8*)(abase + (size_t)(s >> 1) * NH + 32 * (s & 1));
        f32x4 acc[4];
        #pragma unroll
        for (int nt = 0; nt < 4; ++nt) acc[nt] = (f32x4){0.f, 0.f, 0.f, 0.f};
        #pragma unroll
        for (int s = 0; s < 8; ++s)
            #pragma unroll
            for (int nt = 0; nt < 4; ++nt)
                acc[nt] = __builtin_amdgcn_mfma_f32_16x16x32_f16(a[s], b[nt][s], acc[nt], 0, 0, 0);
        // epilogue: relu + bm1, head GEMV, reduce over n within 16-lane groups
        float o0[4], o1[4];
        #pragma unroll
        for (int reg = 0; reg < 4; ++reg) { o0[reg] = 0.f; o1[reg] = 0.f; }
        #pragma unroll
        for (int nt = 0; nt < 4; ++nt)
            #pragma unroll
            for (int reg = 0; reg < 4; ++reg) {
                float v = fmaxf(acc[nt][reg] + bm1v[nt], 0.f);
                o0[reg] = fmaf(v, w20[nt], o0[reg]);
                o1[reg] = fmaf(v, w21[nt], o1[reg]);
            }
        #pragma unroll
        for (int reg = 0; reg < 4; ++reg) {
            #pragma unroll
            for (int m = 8; m > 0; m >>= 1) {
                o0[reg] += __shfl_xor(o0[reg], m);
                o1[reg] += __shfl_xor(o1[reg], m);
            }
        }
        if ((lane & 15) == 0) {
            int rbase = row0 + (lane >> 4) * 4;
            #pragma unroll
            for (int reg = 0; reg < 4; ++reg) {
                out[(rbase + reg) * 2 + 0] = o0[reg] + bm20;
                out[(rbase + reg) * 2 + 1] = o1[reg] + bm21;
            }
        }
    }
}

extern "C" void kernel_launch(void* const* d_in, const int* in_sizes, int n_in,
                              void* d_out, int out_size, void* d_ws, size_t ws_size,
                              hipStream_t stream)
{
    const float* feature = (const float*)d_in[0];
    const int*   src     = (const int*)d_in[1];
    const int*   dst     = (const int*)d_in[2];
    const float* W1      = (const float*)d_in[3];
    const float* b1      = (const float*)d_in[4];
    const float* W2      = (const float*)d_in[5];
    const float* b2      = (const float*)d_in[6];
    const float* thetas  = (const float*)d_in[7];
    const float* Wm1     = (const float*)d_in[8];
    const float* bm1     = (const float*)d_in[9];
    const float* Wm2     = (const float*)d_in[10];
    const float* bm2     = (const float*)d_in[11];
    float* out = (float*)d_out;

    const size_t NH = (size_t)N_NODES * H_FEATS;   // 6.4M elems
    const int NPAD = 100352;
    float*  dinv    = (float*)d_ws;                  // N
    int*    degi    = (int*)(dinv + NPAD);           // N
    int*    rowp    = degi + NPAD;                   // N+1
    int*    bsums   = rowp + NPAD;                   // 512
    int*    degw    = bsums + 512;                   // N*8 (3.2 MB)
    int*    cursorw = degw + NPAD * NWIN;            // N*8 (3.2 MB)
    int*    rowpw   = cursorw + NPAD * NWIN;         // N*8 (3.2 MB)
    int2*   epack   = (int2*)(rowpw + NPAD * NWIN);  // E int2
    __half* Lh      = (__half*)(epack + N_EDGES);    // 4 x NH halfs, contiguous
    __half* Bpack   = Lh + 4 * NH;                   // 16384 halfs (32 KB)
    // total ws use ≈ 76 MB

    hipMemsetAsync(degw,    0, N_NODES * NWIN * sizeof(int), stream);
    hipMemsetAsync(cursorw, 0, N_NODES * NWIN * sizeof(int), stream);

    hist2_kernel<<<2048, 256, 0, stream>>>(src, dst, degw);
    sumdinv_kernel<<<SCAN_BLOCKS, 256, 0, stream>>>(degw, degi, dinv);
    scan1_kernel<<<SCAN_BLOCKS, 256, 0, stream>>>(degi, rowp, bsums);
    scan2_kernel<<<1, 512, 0, stream>>>(bsums);
    scan3_kernel<<<SCAN_BLOCKS, 256, 0, stream>>>(rowp, bsums);
    rowpw_kernel<<<SCAN_BLOCKS, 256, 0, stream>>>(rowp, degw, rowpw);
    fill_kernel<<<2048, 256, 0, stream>>>(src, dst, rowpw, dinv, cursorw, epack);

    wpack_kernel<<<64, 256, 0, stream>>>(thetas, Wm1, Bpack);
    trunk_kernel<<<1563, 256, 0, stream>>>(feature, W1, b1, W2, b2, Lh);  // -> L0h

    for (int k = 1; k <= 3; ++k)
        gather_kernel<<<3125, 256, 0, stream>>>(Lh + (size_t)(k - 1) * NH, rowp, rowpw,
                                                epack, dinv, Lh + (size_t)k * NH);

    final_mfma_kernel<<<391, 256, 0, stream>>>(Lh, Bpack, Wm2, bm1, bm2, out);
}

// Round 13
// 426.614 us; speedup vs baseline: 1.2721x; 1.2721x over previous
//
#include <hip/hip_runtime.h>
#include <hip/hip_fp16.h>
#include <math.h>

#define N_NODES 100000
#define N_EDGES 1600000
#define IN_FEATS 128
#define H_FEATS 64
#define SCAN_BLOCKS 391   // ceil(100000/256)

typedef _Float16 f16x8 __attribute__((ext_vector_type(8)));
typedef float f32x4 __attribute__((ext_vector_type(4)));

// ---------------- int degree histogram ----------------
__global__ __launch_bounds__(256) void hist_kernel(const int* __restrict__ dst,
                                                   int* __restrict__ degi) {
    int tid = blockIdx.x * 256 + threadIdx.x;
    int stride = gridDim.x * 256;
    for (int e = tid; e < N_EDGES; e += stride)
        atomicAdd(&degi[dst[e]], 1);
}

// degi -> dinv = 1/sqrt(max(deg,1))
__global__ __launch_bounds__(256) void dinv_kernel(const int* __restrict__ degi,
                                                   float* __restrict__ dinv) {
    int i = blockIdx.x * 256 + threadIdx.x;
    if (i < N_NODES) dinv[i] = rsqrtf(fmaxf((float)degi[i], 1.0f));
}

// ---------------- 3-kernel exclusive scan of degi -> rowp ----------------
__global__ __launch_bounds__(256) void scan1_kernel(const int* __restrict__ degi,
                                                    int* __restrict__ rowp,
                                                    int* __restrict__ bsums) {
    __shared__ int tmp[256];
    int i = blockIdx.x * 256 + threadIdx.x;
    int v = (i < N_NODES) ? degi[i] : 0;
    tmp[threadIdx.x] = v;
    __syncthreads();
    #pragma unroll
    for (int off = 1; off < 256; off <<= 1) {
        int t = (threadIdx.x >= off) ? tmp[threadIdx.x - off] : 0;
        __syncthreads();
        tmp[threadIdx.x] += t;
        __syncthreads();
    }
    if (i < N_NODES) rowp[i] = tmp[threadIdx.x] - v;
    if (threadIdx.x == 255) bsums[blockIdx.x] = tmp[255];
}

__global__ __launch_bounds__(512) void scan2_kernel(int* __restrict__ bsums) {
    __shared__ int tmp[512];
    int t = threadIdx.x;
    int v = (t < SCAN_BLOCKS) ? bsums[t] : 0;
    tmp[t] = v;
    __syncthreads();
    #pragma unroll
    for (int off = 1; off < 512; off <<= 1) {
        int x = (t >= off) ? tmp[t - off] : 0;
        __syncthreads();
        tmp[t] += x;
        __syncthreads();
    }
    if (t < SCAN_BLOCKS) bsums[t] = tmp[t] - v;
}

__global__ __launch_bounds__(256) void scan3_kernel(int* __restrict__ rowp,
                                                    const int* __restrict__ bsums) {
    int i = blockIdx.x * 256 + threadIdx.x;
    if (i < N_NODES) rowp[i] += bsums[blockIdx.x];
    if (i == N_NODES) rowp[N_NODES] = N_EDGES;
}

// ---------------- fill CSR slots: single packed 8B write per edge ----------------
__global__ __launch_bounds__(256) void fill_kernel(const int* __restrict__ src,
                                                   const int* __restrict__ dst,
                                                   const int* __restrict__ rowp,
                                                   const float* __restrict__ dinv,
                                                   int* __restrict__ cursor,
                                                   int2* __restrict__ epack) {
    int tid = blockIdx.x * 256 + threadIdx.x;
    int stride = gridDim.x * 256;
    for (int e = tid; e < N_EDGES; e += stride) {
        int d = dst[e];
        int s = src[e];
        int slot = rowp[d] + atomicAdd(&cursor[d], 1);
        epack[slot] = make_int2(s, __float_as_int(dinv[s]));
    }
}

// ---------------- Bpack: Weff collapsed + fp16 + MFMA B-fragment order ----------------
// Fragment (s, nt): lane l, elem j holds B[k = 32s + (l>>4)*8 + j][n = nt*16 + (l&15)]
// where B[k][n] = Weff[q = k>>6][f = k&63][n] = sum_c thetas[c][q] * Wm1[c*64+f][n].
__global__ __launch_bounds__(256) void wpack_kernel(const float* __restrict__ thetas,
                                                    const float* __restrict__ Wm1,
                                                    __half* __restrict__ Bpack) {
    int u = blockIdx.x * 256 + threadIdx.x;   // 16384 total
    int j = u & 7, lane = (u >> 3) & 63, frag = u >> 9;
    int nt = frag & 3, s = frag >> 2;
    int k = 32 * s + ((lane >> 4) << 3) + j;
    int q = k >> 6, f = k & 63;
    int n = nt * 16 + (lane & 15);
    float acc = 0.f;
    #pragma unroll
    for (int c = 0; c < 3; ++c)
        acc = fmaf(thetas[c * 4 + q], Wm1[(c * 64 + f) * 64 + n], acc);
    Bpack[u] = __float2half(acc);
}

// ---------------- trunk: h = relu(relu(X@W1+b1)@W2+b2) -> half table L0h ----------------
__global__ __launch_bounds__(256) void trunk_kernel(
    const float* __restrict__ X, const float* __restrict__ W1, const float* __restrict__ b1,
    const float* __restrict__ W2, const float* __restrict__ b2, __half* __restrict__ H)
{
    __shared__ float stage[16][IN_FEATS];   // 8 KB = 512 float4
    __shared__ float part[4][16][64];       // 16 KB
    __shared__ float h1s[16][64];           // 4 KB
    int t = threadIdx.x;
    int wv = __builtin_amdgcn_readfirstlane(t >> 6);
    int lane = t & 63;
    float w1r[32], w2r[16];
    #pragma unroll
    for (int i = 0; i < 32; ++i) w1r[i] = W1[(wv * 32 + i) * 64 + lane];
    #pragma unroll
    for (int i = 0; i < 16; ++i) w2r[i] = W2[(wv * 16 + i) * 64 + lane];
    float b1v = b1[lane], b2v = b2[lane];
    int srow = t >> 5, sf4 = t & 31;
    float4* st4 = (float4*)stage;

    for (int batch = 0; batch < 4; ++batch) {
        int row0 = blockIdx.x * 64 + batch * 16;
        #pragma unroll
        for (int p = 0; p < 2; ++p) {
            int row = row0 + srow + 8 * p;
            if (row >= N_NODES) row = N_NODES - 1;
            st4[t + 256 * p] =
                ((const float4*)(X + (size_t)row * IN_FEATS))[sf4];
        }
        __syncthreads();
        float acc[16];
        #pragma unroll
        for (int r = 0; r < 16; ++r) {
            const float4* xb = (const float4*)&stage[r][wv * 32];   // uniform -> broadcast
            float a = 0.f, b = 0.f;
            #pragma unroll
            for (int i4 = 0; i4 < 8; i4 += 2) {
                float4 v0 = xb[i4], v1 = xb[i4 + 1];
                a = fmaf(v0.x, w1r[i4 * 4 + 0], a);
                a = fmaf(v0.y, w1r[i4 * 4 + 1], a);
                a = fmaf(v0.z, w1r[i4 * 4 + 2], a);
                a = fmaf(v0.w, w1r[i4 * 4 + 3], a);
                b = fmaf(v1.x, w1r[i4 * 4 + 4], b);
                b = fmaf(v1.y, w1r[i4 * 4 + 5], b);
                b = fmaf(v1.z, w1r[i4 * 4 + 6], b);
                b = fmaf(v1.w, w1r[i4 * 4 + 7], b);
            }
            acc[r] = a + b;
        }
        #pragma unroll
        for (int r = 0; r < 16; ++r) part[wv][r][lane] = acc[r];
        __syncthreads();
        #pragma unroll
        for (int rr = 0; rr < 4; ++rr) {
            int r = wv * 4 + rr;
            float y1 = part[0][r][lane] + part[1][r][lane] +
                       part[2][r][lane] + part[3][r][lane] + b1v;
            h1s[r][lane] = fmaxf(y1, 0.f);
        }
        __syncthreads();
        float acc2[16];
        #pragma unroll
        for (int r = 0; r < 16; ++r) {
            const float4* xb = (const float4*)&h1s[r][wv * 16];     // uniform -> broadcast
            float a = 0.f, b = 0.f;
            #pragma unroll
            for (int i4 = 0; i4 < 4; i4 += 2) {
                float4 v0 = xb[i4], v1 = xb[i4 + 1];
                a = fmaf(v0.x, w2r[i4 * 4 + 0], a);
                a = fmaf(v0.y, w2r[i4 * 4 + 1], a);
                a = fmaf(v0.z, w2r[i4 * 4 + 2], a);
                a = fmaf(v0.w, w2r[i4 * 4 + 3], a);
                b = fmaf(v1.x, w2r[i4 * 4 + 4], b);
                b = fmaf(v1.y, w2r[i4 * 4 + 5], b);
                b = fmaf(v1.z, w2r[i4 * 4 + 6], b);
                b = fmaf(v1.w, w2r[i4 * 4 + 7], b);
            }
            acc2[r] = a + b;
        }
        __syncthreads();
        #pragma unroll
        for (int r = 0; r < 16; ++r) part[wv][r][lane] = acc2[r];
        __syncthreads();
        #pragma unroll
        for (int rr = 0; rr < 4; ++rr) {
            int r = wv * 4 + rr;
            int row = row0 + r;
            float y2 = part[0][r][lane] + part[1][r][lane] +
                       part[2][r][lane] + part[3][r][lane] + b2v;
            if (row < N_NODES) H[(size_t)row * 64 + lane] = __float2half(fmaxf(y2, 0.f));
        }
        __syncthreads();
    }
}

// ---------------- gather pass: Fnew[n] = Fprev[n] - dinv[n]*sum_e w_e*Fprev[s_e]
// Half-wave rows: lanes 0-31 handle edge j+2i, lanes 32-63 edge j+2i+1; each
// lane reads 4B (__half2) of the 128B row -> 16 edges in flight per wave
// (2x the memory-level parallelism of the full-wave layout). Cross-half
// feature reduce via shfl_xor(32); half-0 lanes write the __half2 result.
__global__ __launch_bounds__(256) void gather_kernel(
    const __half* __restrict__ Fprev, const int* __restrict__ rowp,
    const int2* __restrict__ epack, const float* __restrict__ dinv,
    __half* __restrict__ Fnew)
{
    int wv = __builtin_amdgcn_readfirstlane(threadIdx.x >> 6);
    int wid = blockIdx.x * 4 + wv;   // node id (uniform); grid covers N exactly
    int lane = threadIdx.x & 63;
    int half = lane >> 5;            // which edge of the pair
    int sub = lane & 31;             // feature-pair index: features 2*sub, 2*sub+1
    int beg = rowp[wid], end = rowp[wid + 1];
    float a0 = 0.f, a1 = 0.f;
    int j = beg;
    for (; j + 15 < end; j += 16) {
        int2 e0 = epack[j + 0 + half],  e1 = epack[j + 2 + half];
        int2 e2 = epack[j + 4 + half],  e3 = epack[j + 6 + half];
        int2 e4 = epack[j + 8 + half],  e5 = epack[j + 10 + half];
        int2 e6 = epack[j + 12 + half], e7 = epack[j + 14 + half];
        uint v0 = *(const uint*)(Fprev + (size_t)e0.x * 64 + sub * 2);
        uint v1 = *(const uint*)(Fprev + (size_t)e1.x * 64 + sub * 2);
        uint v2 = *(const uint*)(Fprev + (size_t)e2.x * 64 + sub * 2);
        uint v3 = *(const uint*)(Fprev + (size_t)e3.x * 64 + sub * 2);
        uint v4 = *(const uint*)(Fprev + (size_t)e4.x * 64 + sub * 2);
        uint v5 = *(const uint*)(Fprev + (size_t)e5.x * 64 + sub * 2);
        uint v6 = *(const uint*)(Fprev + (size_t)e6.x * 64 + sub * 2);
        uint v7 = *(const uint*)(Fprev + (size_t)e7.x * 64 + sub * 2);
        float2 f;
        f = __half22float2(*reinterpret_cast<__half2*>(&v0));
        a0 = fmaf(f.x, __int_as_float(e0.y), a0); a1 = fmaf(f.y, __int_as_float(e0.y), a1);
        f = __half22float2(*reinterpret_cast<__half2*>(&v1));
        a0 = fmaf(f.x, __int_as_float(e1.y), a0); a1 = fmaf(f.y, __int_as_float(e1.y), a1);
        f = __half22float2(*reinterpret_cast<__half2*>(&v2));
        a0 = fmaf(f.x, __int_as_float(e2.y), a0); a1 = fmaf(f.y, __int_as_float(e2.y), a1);
        f = __half22float2(*reinterpret_cast<__half2*>(&v3));
        a0 = fmaf(f.x, __int_as_float(e3.y), a0); a1 = fmaf(f.y, __int_as_float(e3.y), a1);
        f = __half22float2(*reinterpret_cast<__half2*>(&v4));
        a0 = fmaf(f.x, __int_as_float(e4.y), a0); a1 = fmaf(f.y, __int_as_float(e4.y), a1);
        f = __half22float2(*reinterpret_cast<__half2*>(&v5));
        a0 = fmaf(f.x, __int_as_float(e5.y), a0); a1 = fmaf(f.y, __int_as_float(e5.y), a1);
        f = __half22float2(*reinterpret_cast<__half2*>(&v6));
        a0 = fmaf(f.x, __int_as_float(e6.y), a0); a1 = fmaf(f.y, __int_as_float(e6.y), a1);
        f = __half22float2(*reinterpret_cast<__half2*>(&v7));
        a0 = fmaf(f.x, __int_as_float(e7.y), a0); a1 = fmaf(f.y, __int_as_float(e7.y), a1);
    }
    for (; j + 1 < end; j += 2) {
        int2 e = epack[j + half];
        uint v = *(const uint*)(Fprev + (size_t)e.x * 64 + sub * 2);
        float2 f = __half22float2(*reinterpret_cast<__half2*>(&v));
        a0 = fmaf(f.x, __int_as_float(e.y), a0);
        a1 = fmaf(f.y, __int_as_float(e.y), a1);
    }
    if (j < end && half == 0) {      // odd tail edge: half-0 lanes only
        int2 e = epack[j];
        uint v = *(const uint*)(Fprev + (size_t)e.x * 64 + sub * 2);
        float2 f = __half22float2(*reinterpret_cast<__half2*>(&v));
        a0 = fmaf(f.x, __int_as_float(e.y), a0);
        a1 = fmaf(f.y, __int_as_float(e.y), a1);
    }
    a0 += __shfl_xor(a0, 32);
    a1 += __shfl_xor(a1, 32);
    if (half == 0) {
        float di = dinv[wid];
        uint sv = *(const uint*)(Fprev + (size_t)wid * 64 + sub * 2);
        float2 sf = __half22float2(*reinterpret_cast<__half2*>(&sv));
        __half2 r = __floats2half2_rn(sf.x - a0 * di, sf.y - a1 * di);
        *(__half2*)(Fnew + (size_t)wid * 64 + sub * 2) = r;
    }
}

// ---------------- final (MFMA): out = relu(A@B + bm1) @ Wm2 + bm2 ----------------
// A[100000 x 256] fp16 = [L0|L1|L2|L3] column-blocked (Lh contiguous);
// B[256 x 64] fp16 pre-packed in fragment order (Bpack).
// D: col n = nt*16 + (l&15), row = row0 + (l>>4)*4 + reg   [m89 layout]
__global__ __launch_bounds__(256) void final_mfma_kernel(
    const __half* __restrict__ L0h, const __half* __restrict__ Bpack,
    const float* __restrict__ Wm2, const float* __restrict__ bm1,
    const float* __restrict__ bm2, float* __restrict__ out)
{
    const size_t NH = (size_t)N_NODES * 64;
    int t = threadIdx.x;
    int wv = t >> 6;
    int lane = t & 63;
    int gw = blockIdx.x * 4 + wv;          // 1564 waves

    // preload all 32 B fragments (128 VGPRs)
    const f16x8* bp = (const f16x8*)Bpack;
    f16x8 b[4][8];
    #pragma unroll
    for (int s = 0; s < 8; ++s)
        #pragma unroll
        for (int nt = 0; nt < 4; ++nt)
            b[nt][s] = bp[(s * 4 + nt) * 64 + lane];

    // per-lane head constants: n = nt*16 + (lane&15)
    float bm1v[4], w20[4], w21[4];
    #pragma unroll
    for (int nt = 0; nt < 4; ++nt) {
        int n = nt * 16 + (lane & 15);
        bm1v[nt] = bm1[n];
        w20[nt] = Wm2[n * 2 + 0];
        w21[nt] = Wm2[n * 2 + 1];
    }
    float bm20 = bm2[0], bm21 = bm2[1];

    for (int u = 0; u < 4; ++u) {
        int tile = gw * 4 + u;
        if (tile >= 6250) break;           // 6250 * 16 = 100000 exactly
        int row0 = tile * 16;
        const __half* abase = L0h + (size_t)(row0 + (lane & 15)) * 64 + ((lane >> 4) << 3);
        f16x8 a[8];
        #pragma unroll
        for (int s = 0; s < 8; ++s)
            a[s] = *(const f16x8*)(abase + (size_t)(s >> 1) * NH + 32 * (s & 1));
        f32x4 acc[4];
        #pragma unroll
        for (int nt = 0; nt < 4; ++nt) acc[nt] = (f32x4){0.f, 0.f, 0.f, 0.f};
        #pragma unroll
        for (int s = 0; s < 8; ++s)
            #pragma unroll
            for (int nt = 0; nt < 4; ++nt)
                acc[nt] = __builtin_amdgcn_mfma_f32_16x16x32_f16(a[s], b[nt][s], acc[nt], 0, 0, 0);
        // epilogue: relu + bm1, head GEMV, reduce over n within 16-lane groups
        float o0[4], o1[4];
        #pragma unroll
        for (int reg = 0; reg < 4; ++reg) { o0[reg] = 0.f; o1[reg] = 0.f; }
        #pragma unroll
        for (int nt = 0; nt < 4; ++nt)
            #pragma unroll
            for (int reg = 0; reg < 4; ++reg) {
                float v = fmaxf(acc[nt][reg] + bm1v[nt], 0.f);
                o0[reg] = fmaf(v, w20[nt], o0[reg]);
                o1[reg] = fmaf(v, w21[nt], o1[reg]);
            }
        #pragma unroll
        for (int reg = 0; reg < 4; ++reg) {
            #pragma unroll
            for (int m = 8; m > 0; m >>= 1) {
                o0[reg] += __shfl_xor(o0[reg], m);
                o1[reg] += __shfl_xor(o1[reg], m);
            }
        }
        if ((lane & 15) == 0) {
            int rbase = row0 + (lane >> 4) * 4;
            #pragma unroll
            for (int reg = 0; reg < 4; ++reg) {
                out[(rbase + reg) * 2 + 0] = o0[reg] + bm20;
                out[(rbase + reg) * 2 + 1] = o1[reg] + bm21;
            }
        }
    }
}

extern "C" void kernel_launch(void* const* d_in, const int* in_sizes, int n_in,
                              void* d_out, int out_size, void* d_ws, size_t ws_size,
                              hipStream_t stream)
{
    const float* feature = (const float*)d_in[0];
    const int*   src     = (const int*)d_in[1];
    const int*   dst     = (const int*)d_in[2];
    const float* W1      = (const float*)d_in[3];
    const float* b1      = (const float*)d_in[4];
    const float* W2      = (const float*)d_in[5];
    const float* b2      = (const float*)d_in[6];
    const float* thetas  = (const float*)d_in[7];
    const float* Wm1     = (const float*)d_in[8];
    const float* bm1     = (const float*)d_in[9];
    const float* Wm2     = (const float*)d_in[10];
    const float* bm2     = (const float*)d_in[11];
    float* out = (float*)d_out;

    const size_t NH = (size_t)N_NODES * H_FEATS;   // 6.4M elems
    const int NPAD = 100352;
    float*  dinv   = (float*)d_ws;                  // N
    int*    degi   = (int*)(dinv + NPAD);           // N
    int*    rowp   = degi + NPAD;                   // N+1
    int*    bsums  = rowp + NPAD;                   // 512
    int*    cursor = bsums + 512;                   // N
    int2*   epack  = (int2*)(cursor + NPAD);        // E int2
    __half* Lh     = (__half*)(epack + N_EDGES);    // 4 x NH halfs, contiguous, 128B-aligned
    __half* Bpack  = Lh + 4 * NH;                   // 16384 halfs (32 KB)
    // total ws use ≈ 66 MB

    hipMemsetAsync(degi,   0, N_NODES * sizeof(int), stream);
    hipMemsetAsync(cursor, 0, N_NODES * sizeof(int), stream);

    hist_kernel<<<1024, 256, 0, stream>>>(dst, degi);
    dinv_kernel<<<(N_NODES + 255) / 256, 256, 0, stream>>>(degi, dinv);
    scan1_kernel<<<SCAN_BLOCKS, 256, 0, stream>>>(degi, rowp, bsums);
    scan2_kernel<<<1, 512, 0, stream>>>(bsums);
    scan3_kernel<<<SCAN_BLOCKS, 256, 0, stream>>>(rowp, bsums);
    fill_kernel<<<2048, 256, 0, stream>>>(src, dst, rowp, dinv, cursor, epack);

    wpack_kernel<<<64, 256, 0, stream>>>(thetas, Wm1, Bpack);
    trunk_kernel<<<1563, 256, 0, stream>>>(feature, W1, b1, W2, b2, Lh);  // -> L0h

    for (int k = 1; k <= 3; ++k)
        gather_kernel<<<25000, 256, 0, stream>>>(Lh + (size_t)(k - 1) * NH, rowp, epack,
                                                 dinv, Lh + (size_t)k * NH);

    final_mfma_kernel<<<391, 256, 0, stream>>>(Lh, Bpack, Wm2, bm1, bm2, out);
}

// Round 14
// 384.991 us; speedup vs baseline: 1.4096x; 1.1081x over previous
//
#include <hip/hip_runtime.h>
#include <hip/hip_fp16.h>
#include <math.h>

#define N_NODES 100000
#define N_EDGES 1600000
#define IN_FEATS 128
#define H_FEATS 64
#define SCAN_BLOCKS 391   // ceil(100000/256)
#define NWIN 8
#define WIN_SZ 12500      // N_NODES / NWIN exactly

typedef _Float16 f16x8 __attribute__((ext_vector_type(8)));
typedef float f32x4 __attribute__((ext_vector_type(4)));

// ---------------- int degree histogram ----------------
__global__ __launch_bounds__(256) void hist_kernel(const int* __restrict__ dst,
                                                   int* __restrict__ degi) {
    int tid = blockIdx.x * 256 + threadIdx.x;
    int stride = gridDim.x * 256;
    for (int e = tid; e < N_EDGES; e += stride)
        atomicAdd(&degi[dst[e]], 1);
}

// degi -> dinv = 1/sqrt(max(deg,1))
__global__ __launch_bounds__(256) void dinv_kernel(const int* __restrict__ degi,
                                                   float* __restrict__ dinv) {
    int i = blockIdx.x * 256 + threadIdx.x;
    if (i < N_NODES) dinv[i] = rsqrtf(fmaxf((float)degi[i], 1.0f));
}

// ---------------- 3-kernel exclusive scan of degi -> rowp ----------------
__global__ __launch_bounds__(256) void scan1_kernel(const int* __restrict__ degi,
                                                    int* __restrict__ rowp,
                                                    int* __restrict__ bsums) {
    __shared__ int tmp[256];
    int i = blockIdx.x * 256 + threadIdx.x;
    int v = (i < N_NODES) ? degi[i] : 0;
    tmp[threadIdx.x] = v;
    __syncthreads();
    #pragma unroll
    for (int off = 1; off < 256; off <<= 1) {
        int t = (threadIdx.x >= off) ? tmp[threadIdx.x - off] : 0;
        __syncthreads();
        tmp[threadIdx.x] += t;
        __syncthreads();
    }
    if (i < N_NODES) rowp[i] = tmp[threadIdx.x] - v;
    if (threadIdx.x == 255) bsums[blockIdx.x] = tmp[255];
}

__global__ __launch_bounds__(512) void scan2_kernel(int* __restrict__ bsums) {
    __shared__ int tmp[512];
    int t = threadIdx.x;
    int v = (t < SCAN_BLOCKS) ? bsums[t] : 0;
    tmp[t] = v;
    __syncthreads();
    #pragma unroll
    for (int off = 1; off < 512; off <<= 1) {
        int x = (t >= off) ? tmp[t - off] : 0;
        __syncthreads();
        tmp[t] += x;
        __syncthreads();
    }
    if (t < SCAN_BLOCKS) bsums[t] = tmp[t] - v;
}

__global__ __launch_bounds__(256) void scan3_kernel(int* __restrict__ rowp,
                                                    const int* __restrict__ bsums) {
    int i = blockIdx.x * 256 + threadIdx.x;
    if (i < N_NODES) rowp[i] += bsums[blockIdx.x];
    if (i == N_NODES) rowp[N_NODES] = N_EDGES;
}

// ---------------- fill CSR slots: XCC_ID-phased windowed scatter ----------------
// Each block owns a private 782-edge chunk (6KB, cache-resident on re-scan) and
// sweeps 8 dst-window phases STARTING AT ITS OWN (runtime-read) XCD id. During
// phase p, all blocks on XCD x scatter into window (x+p)&7's 1.6MB epack span;
// no other XCD writes that span concurrently -> a 64B line's 8 slots merge in
// one L2 before write-back (R11 failed because blockIdx%8 != XCD; HW_REG_XCC_ID
// is ground truth, m09). Every edge written exactly once regardless of
// placement -> correctness is dispatch-independent.
__global__ __launch_bounds__(256) void fill_kernel(const int* __restrict__ src,
                                                   const int* __restrict__ dst,
                                                   const int* __restrict__ rowp,
                                                   const float* __restrict__ dinv,
                                                   int* __restrict__ cursor,
                                                   int2* __restrict__ epack) {
    const int CHUNK = 782;                 // 2048 * 782 >= N_EDGES
    int e0 = blockIdx.x * CHUNK;
    int e1 = e0 + CHUNK; if (e1 > N_EDGES) e1 = N_EDGES;
    unsigned xcd;
    asm("s_getreg_b32 %0, hwreg(HW_REG_XCC_ID)" : "=s"(xcd));
    xcd &= 7;
    for (int p = 0; p < NWIN; ++p) {
        int w = (xcd + p) & 7;
        int dlo = w * WIN_SZ, dhi = dlo + WIN_SZ;
        for (int e = e0 + threadIdx.x; e < e1; e += 256) {
            int d = dst[e];
            if (d >= dlo && d < dhi) {
                int s = src[e];
                int slot = rowp[d] + atomicAdd(&cursor[d], 1);
                epack[slot] = make_int2(s, __float_as_int(dinv[s]));
            }
        }
    }
}

// ---------------- Bpack: Weff collapsed + fp16 + MFMA B-fragment order ----------------
// Fragment (s, nt): lane l, elem j holds B[k = 32s + (l>>4)*8 + j][n = nt*16 + (l&15)]
// where B[k][n] = Weff[q = k>>6][f = k&63][n] = sum_c thetas[c][q] * Wm1[c*64+f][n].
__global__ __launch_bounds__(256) void wpack_kernel(const float* __restrict__ thetas,
                                                    const float* __restrict__ Wm1,
                                                    __half* __restrict__ Bpack) {
    int u = blockIdx.x * 256 + threadIdx.x;   // 16384 total
    int j = u & 7, lane = (u >> 3) & 63, frag = u >> 9;
    int nt = frag & 3, s = frag >> 2;
    int k = 32 * s + ((lane >> 4) << 3) + j;
    int q = k >> 6, f = k & 63;
    int n = nt * 16 + (lane & 15);
    float acc = 0.f;
    #pragma unroll
    for (int c = 0; c < 3; ++c)
        acc = fmaf(thetas[c * 4 + q], Wm1[(c * 64 + f) * 64 + n], acc);
    Bpack[u] = __float2half(acc);
}

// ---------------- trunk: h = relu(relu(X@W1+b1)@W2+b2) -> half table L0h ----------------
__global__ __launch_bounds__(256) void trunk_kernel(
    const float* __restrict__ X, const float* __restrict__ W1, const float* __restrict__ b1,
    const float* __restrict__ W2, const float* __restrict__ b2, __half* __restrict__ H)
{
    __shared__ float stage[16][IN_FEATS];   // 8 KB = 512 float4
    __shared__ float part[4][16][64];       // 16 KB
    __shared__ float h1s[16][64];           // 4 KB
    int t = threadIdx.x;
    int wv = __builtin_amdgcn_readfirstlane(t >> 6);
    int lane = t & 63;
    float w1r[32], w2r[16];
    #pragma unroll
    for (int i = 0; i < 32; ++i) w1r[i] = W1[(wv * 32 + i) * 64 + lane];
    #pragma unroll
    for (int i = 0; i < 16; ++i) w2r[i] = W2[(wv * 16 + i) * 64 + lane];
    float b1v = b1[lane], b2v = b2[lane];
    int srow = t >> 5, sf4 = t & 31;
    float4* st4 = (float4*)stage;

    for (int batch = 0; batch < 4; ++batch) {
        int row0 = blockIdx.x * 64 + batch * 16;
        #pragma unroll
        for (int p = 0; p < 2; ++p) {
            int row = row0 + srow + 8 * p;
            if (row >= N_NODES) row = N_NODES - 1;
            st4[t + 256 * p] =
                ((const float4*)(X + (size_t)row * IN_FEATS))[sf4];
        }
        __syncthreads();
        float acc[16];
        #pragma unroll
        for (int r = 0; r < 16; ++r) {
            const float4* xb = (const float4*)&stage[r][wv * 32];   // uniform -> broadcast
            float a = 0.f, b = 0.f;
            #pragma unroll
            for (int i4 = 0; i4 < 8; i4 += 2) {
                float4 v0 = xb[i4], v1 = xb[i4 + 1];
                a = fmaf(v0.x, w1r[i4 * 4 + 0], a);
                a = fmaf(v0.y, w1r[i4 * 4 + 1], a);
                a = fmaf(v0.z, w1r[i4 * 4 + 2], a);
                a = fmaf(v0.w, w1r[i4 * 4 + 3], a);
                b = fmaf(v1.x, w1r[i4 * 4 + 4], b);
                b = fmaf(v1.y, w1r[i4 * 4 + 5], b);
                b = fmaf(v1.z, w1r[i4 * 4 + 6], b);
                b = fmaf(v1.w, w1r[i4 * 4 + 7], b);
            }
            acc[r] = a + b;
        }
        #pragma unroll
        for (int r = 0; r < 16; ++r) part[wv][r][lane] = acc[r];
        __syncthreads();
        #pragma unroll
        for (int rr = 0; rr < 4; ++rr) {
            int r = wv * 4 + rr;
            float y1 = part[0][r][lane] + part[1][r][lane] +
                       part[2][r][lane] + part[3][r][lane] + b1v;
            h1s[r][lane] = fmaxf(y1, 0.f);
        }
        __syncthreads();
        float acc2[16];
        #pragma unroll
        for (int r = 0; r < 16; ++r) {
            const float4* xb = (const float4*)&h1s[r][wv * 16];     // uniform -> broadcast
            float a = 0.f, b = 0.f;
            #pragma unroll
            for (int i4 = 0; i4 < 4; i4 += 2) {
                float4 v0 = xb[i4], v1 = xb[i4 + 1];
                a = fmaf(v0.x, w2r[i4 * 4 + 0], a);
                a = fmaf(v0.y, w2r[i4 * 4 + 1], a);
                a = fmaf(v0.z, w2r[i4 * 4 + 2], a);
                a = fmaf(v0.w, w2r[i4 * 4 + 3], a);
                b = fmaf(v1.x, w2r[i4 * 4 + 4], b);
                b = fmaf(v1.y, w2r[i4 * 4 + 5], b);
                b = fmaf(v1.z, w2r[i4 * 4 + 6], b);
                b = fmaf(v1.w, w2r[i4 * 4 + 7], b);
            }
            acc2[r] = a + b;
        }
        __syncthreads();
        #pragma unroll
        for (int r = 0; r < 16; ++r) part[wv][r][lane] = acc2[r];
        __syncthreads();
        #pragma unroll
        for (int rr = 0; rr < 4; ++rr) {
            int r = wv * 4 + rr;
            int row = row0 + r;
            float y2 = part[0][r][lane] + part[1][r][lane] +
                       part[2][r][lane] + part[3][r][lane] + b2v;
            if (row < N_NODES) H[(size_t)row * 64 + lane] = __float2half(fmaxf(y2, 0.f));
        }
        __syncthreads();
    }
}

// ---------------- gather pass: Fnew[n] = Fprev[n] - dinv[n]*sum_e w_e*Fprev[s_e]
// half tables (128B row per edge), fp32 accumulate; one wave per node. (R10 form)
__global__ __launch_bounds__(256) void gather_kernel(
    const __half* __restrict__ Fprev, const int* __restrict__ rowp,
    const int2* __restrict__ epack, const float* __restrict__ dinv,
    __half* __restrict__ Fnew)
{
    int wv = __builtin_amdgcn_readfirstlane(threadIdx.x >> 6);
    int wid = blockIdx.x * 4 + wv;   // node id (uniform)
    int lane = threadIdx.x & 63;
    int beg = rowp[wid], end = rowp[wid + 1];
    float acc = 0.0f;
    int j = beg;
    for (; j + 7 < end; j += 8) {
        int2 e0 = epack[j],     e1 = epack[j + 1], e2 = epack[j + 2], e3 = epack[j + 3];
        int2 e4 = epack[j + 4], e5 = epack[j + 5], e6 = epack[j + 6], e7 = epack[j + 7];
        float v0 = __half2float(Fprev[(size_t)e0.x * 64 + lane]);
        float v1 = __half2float(Fprev[(size_t)e1.x * 64 + lane]);
        float v2 = __half2float(Fprev[(size_t)e2.x * 64 + lane]);
        float v3 = __half2float(Fprev[(size_t)e3.x * 64 + lane]);
        float v4 = __half2float(Fprev[(size_t)e4.x * 64 + lane]);
        float v5 = __half2float(Fprev[(size_t)e5.x * 64 + lane]);
        float v6 = __half2float(Fprev[(size_t)e6.x * 64 + lane]);
        float v7 = __half2float(Fprev[(size_t)e7.x * 64 + lane]);
        acc = fmaf(v0, __int_as_float(e0.y), acc);
        acc = fmaf(v1, __int_as_float(e1.y), acc);
        acc = fmaf(v2, __int_as_float(e2.y), acc);
        acc = fmaf(v3, __int_as_float(e3.y), acc);
        acc = fmaf(v4, __int_as_float(e4.y), acc);
        acc = fmaf(v5, __int_as_float(e5.y), acc);
        acc = fmaf(v6, __int_as_float(e6.y), acc);
        acc = fmaf(v7, __int_as_float(e7.y), acc);
    }
    for (; j < end; ++j) {
        int2 e = epack[j];
        acc = fmaf(__half2float(Fprev[(size_t)e.x * 64 + lane]), __int_as_float(e.y), acc);
    }
    float self = __half2float(Fprev[(size_t)wid * 64 + lane]);
    Fnew[(size_t)wid * 64 + lane] = __float2half(self - acc * dinv[wid]);
}

// ---------------- final (MFMA): out = relu(A@B + bm1) @ Wm2 + bm2 ----------------
// A[100000 x 256] fp16 = [L0|L1|L2|L3] column-blocked (Lh contiguous);
// B[256 x 64] fp16 pre-packed in fragment order (Bpack).
// D: col n = nt*16 + (l&15), row = row0 + (l>>4)*4 + reg   [m89 layout]
__global__ __launch_bounds__(256) void final_mfma_kernel(
    const __half* __restrict__ L0h, const __half* __restrict__ Bpack,
    const float* __restrict__ Wm2, const float* __restrict__ bm1,
    const float* __restrict__ bm2, float* __restrict__ out)
{
    const size_t NH = (size_t)N_NODES * 64;
    int t = threadIdx.x;
    int wv = t >> 6;
    int lane = t & 63;
    int gw = blockIdx.x * 4 + wv;          // 1564 waves

    // preload all 32 B fragments (128 VGPRs)
    const f16x8* bp = (const f16x8*)Bpack;
    f16x8 b[4][8];
    #pragma unroll
    for (int s = 0; s < 8; ++s)
        #pragma unroll
        for (int nt = 0; nt < 4; ++nt)
            b[nt][s] = bp[(s * 4 + nt) * 64 + lane];

    // per-lane head constants: n = nt*16 + (lane&15)
    float bm1v[4], w20[4], w21[4];
    #pragma unroll
    for (int nt = 0; nt < 4; ++nt) {
        int n = nt * 16 + (lane & 15);
        bm1v[nt] = bm1[n];
        w20[nt] = Wm2[n * 2 + 0];
        w21[nt] = Wm2[n * 2 + 1];
    }
    float bm20 = bm2[0], bm21 = bm2[1];

    for (int u = 0; u < 4; ++u) {
        int tile = gw * 4 + u;
        if (tile >= 6250) break;           // 6250 * 16 = 100000 exactly
        int row0 = tile * 16;
        const __half* abase = L0h + (size_t)(row0 + (lane & 15)) * 64 + ((lane >> 4) << 3);
        f16x8 a[8];
        #pragma unroll
        for (int s = 0; s < 8; ++s)
            a[s] = *(const f16x8*)(abase + (size_t)(s >> 1) * NH + 32 * (s & 1));
        f32x4 acc[4];
        #pragma unroll
        for (int nt = 0; nt < 4; ++nt) acc[nt] = (f32x4){0.f, 0.f, 0.f, 0.f};
        #pragma unroll
        for (int s = 0; s < 8; ++s)
            #pragma unroll
            for (int nt = 0; nt < 4; ++nt)
                acc[nt] = __builtin_amdgcn_mfma_f32_16x16x32_f16(a[s], b[nt][s], acc[nt], 0, 0, 0);
        // epilogue: relu + bm1, head GEMV, reduce over n within 16-lane groups
        float o0[4], o1[4];
        #pragma unroll
        for (int reg = 0; reg < 4; ++reg) { o0[reg] = 0.f; o1[reg] = 0.f; }
        #pragma unroll
        for (int nt = 0; nt < 4; ++nt)
            #pragma unroll
            for (int reg = 0; reg < 4; ++reg) {
                float v = fmaxf(acc[nt][reg] + bm1v[nt], 0.f);
                o0[reg] = fmaf(v, w20[nt], o0[reg]);
                o1[reg] = fmaf(v, w21[nt], o1[reg]);
            }
        #pragma unroll
        for (int reg = 0; reg < 4; ++reg) {
            #pragma unroll
            for (int m = 8; m > 0; m >>= 1) {
                o0[reg] += __shfl_xor(o0[reg], m);
                o1[reg] += __shfl_xor(o1[reg], m);
            }
        }
        if ((lane & 15) == 0) {
            int rbase = row0 + (lane >> 4) * 4;
            #pragma unroll
            for (int reg = 0; reg < 4; ++reg) {
                out[(rbase + reg) * 2 + 0] = o0[reg] + bm20;
                out[(rbase + reg) * 2 + 1] = o1[reg] + bm21;
            }
        }
    }
}

extern "C" void kernel_launch(void* const* d_in, const int* in_sizes, int n_in,
                              void* d_out, int out_size, void* d_ws, size_t ws_size,
                              hipStream_t stream)
{
    const float* feature = (const float*)d_in[0];
    const int*   src     = (const int*)d_in[1];
    const int*   dst     = (const int*)d_in[2];
    const float* W1      = (const float*)d_in[3];
    const float* b1      = (const float*)d_in[4];
    const float* W2      = (const float*)d_in[5];
    const float* b2      = (const float*)d_in[6];
    const float* thetas  = (const float*)d_in[7];
    const float* Wm1     = (const float*)d_in[8];
    const float* bm1     = (const float*)d_in[9];
    const float* Wm2     = (const float*)d_in[10];
    const float* bm2     = (const float*)d_in[11];
    float* out = (float*)d_out;

    const size_t NH = (size_t)N_NODES * H_FEATS;   // 6.4M elems
    const int NPAD = 100352;
    float*  dinv   = (float*)d_ws;                  // N
    int*    degi   = (int*)(dinv + NPAD);           // N
    int*    rowp   = degi + NPAD;                   // N+1
    int*    bsums  = rowp + NPAD;                   // 512
    int*    cursor = bsums + 512;                   // N
    int2*   epack  = (int2*)(cursor + NPAD);        // E int2
    __half* Lh     = (__half*)(epack + N_EDGES);    // 4 x NH halfs, contiguous
    __half* Bpack  = Lh + 4 * NH;                   // 16384 halfs (32 KB)
    // total ws use ≈ 66 MB

    hipMemsetAsync(degi,   0, N_NODES * sizeof(int), stream);
    hipMemsetAsync(cursor, 0, N_NODES * sizeof(int), stream);

    hist_kernel<<<1024, 256, 0, stream>>>(dst, degi);
    dinv_kernel<<<(N_NODES + 255) / 256, 256, 0, stream>>>(degi, dinv);
    scan1_kernel<<<SCAN_BLOCKS, 256, 0, stream>>>(degi, rowp, bsums);
    scan2_kernel<<<1, 512, 0, stream>>>(bsums);
    scan3_kernel<<<SCAN_BLOCKS, 256, 0, stream>>>(rowp, bsums);
    fill_kernel<<<2048, 256, 0, stream>>>(src, dst, rowp, dinv, cursor, epack);

    wpack_kernel<<<64, 256, 0, stream>>>(thetas, Wm1, Bpack);
    trunk_kernel<<<1563, 256, 0, stream>>>(feature, W1, b1, W2, b2, Lh);  // -> L0h

    for (int k = 1; k <= 3; ++k)
        gather_kernel<<<25000, 256, 0, stream>>>(Lh + (size_t)(k - 1) * NH, rowp, epack,
                                                 dinv, Lh + (size_t)k * NH);

    final_mfma_kernel<<<391, 256, 0, stream>>>(Lh, Bpack, Wm2, bm1, bm2, out);
}

// Round 15
// 352.767 us; speedup vs baseline: 1.5384x; 1.0913x over previous
//
#include <hip/hip_runtime.h>
#include <hip/hip_fp16.h>
#include <math.h>

#define N_NODES 100000
#define N_EDGES 1600000
#define IN_FEATS 128
#define H_FEATS 64
#define SCAN_BLOCKS 391   // ceil(100000/256)
#define NB_TRUNK 1563     // trunk tiles (64 rows each)
#define NB_FILL 2048      // fill grid-stride blocks
#define NB_WPACK 64
// mega grid: [0,3126) even->trunk, odd->fill; [3126,3611) fill; [3611,3675) wpack
#define NB_MEGA (2 * NB_TRUNK + (NB_FILL - NB_TRUNK) + NB_WPACK)

typedef _Float16 f16x8 __attribute__((ext_vector_type(8)));
typedef float f32x4 __attribute__((ext_vector_type(4)));

// ---------------- int degree histogram ----------------
__global__ __launch_bounds__(256) void hist_kernel(const int* __restrict__ dst,
                                                   int* __restrict__ degi) {
    int tid = blockIdx.x * 256 + threadIdx.x;
    int stride = gridDim.x * 256;
    for (int e = tid; e < N_EDGES; e += stride)
        atomicAdd(&degi[dst[e]], 1);
}

// ---------------- scan1: block-local exclusive scan of degi + dinv fold ----------------
__global__ __launch_bounds__(256) void scan1_kernel(const int* __restrict__ degi,
                                                    int* __restrict__ rowp,
                                                    int* __restrict__ bsums,
                                                    float* __restrict__ dinv) {
    __shared__ int tmp[256];
    int i = blockIdx.x * 256 + threadIdx.x;
    int v = (i < N_NODES) ? degi[i] : 0;
    tmp[threadIdx.x] = v;
    __syncthreads();
    #pragma unroll
    for (int off = 1; off < 256; off <<= 1) {
        int t = (threadIdx.x >= off) ? tmp[threadIdx.x - off] : 0;
        __syncthreads();
        tmp[threadIdx.x] += t;
        __syncthreads();
    }
    if (i < N_NODES) {
        rowp[i] = tmp[threadIdx.x] - v;
        dinv[i] = rsqrtf(fmaxf((float)v, 1.0f));
    }
    if (threadIdx.x == 255) bsums[blockIdx.x] = tmp[255];
}

__global__ __launch_bounds__(512) void scan2_kernel(int* __restrict__ bsums) {
    __shared__ int tmp[512];
    int t = threadIdx.x;
    int v = (t < SCAN_BLOCKS) ? bsums[t] : 0;
    tmp[t] = v;
    __syncthreads();
    #pragma unroll
    for (int off = 1; off < 512; off <<= 1) {
        int x = (t >= off) ? tmp[t - off] : 0;
        __syncthreads();
        tmp[t] += x;
        __syncthreads();
    }
    if (t < SCAN_BLOCKS) bsums[t] = tmp[t] - v;
}

__global__ __launch_bounds__(256) void scan3_kernel(int* __restrict__ rowp,
                                                    const int* __restrict__ bsums) {
    int i = blockIdx.x * 256 + threadIdx.x;
    if (i < N_NODES) rowp[i] += bsums[blockIdx.x];
    if (i == N_NODES) rowp[N_NODES] = N_EDGES;
}

// ---------------- mega kernel: trunk + fill + wpack co-scheduled ----------------
// trunk (VALU/LDS-bound) blocks interleave 1:1 with fill (atomic-latency-bound)
// blocks so every CU hosts both: trunk's FMAs execute in fill's atomic-wait
// bubbles. Roles are independent: fill needs rowp/dinv (prior kernels); trunk
// only X/W; wpack only thetas/Wm1.
__global__ __launch_bounds__(256) void mega_kernel(
    // trunk args
    const float* __restrict__ X, const float* __restrict__ W1, const float* __restrict__ b1,
    const float* __restrict__ W2, const float* __restrict__ b2, __half* __restrict__ H,
    // fill args
    const int* __restrict__ src, const int* __restrict__ dst,
    const int* __restrict__ rowp, const float* __restrict__ dinv,
    int* __restrict__ cursor, int2* __restrict__ epack,
    // wpack args
    const float* __restrict__ thetas, const float* __restrict__ Wm1,
    __half* __restrict__ Bpack)
{
    int b = blockIdx.x;
    int t = threadIdx.x;

    // ---- role dispatch ----
    bool is_trunk = (b < 2 * NB_TRUNK) && ((b & 1) == 0);
    if (is_trunk) {
        int tb = b >> 1;   // trunk tile id, [0, NB_TRUNK)
        __shared__ float stage[16][IN_FEATS];   // 8 KB
        __shared__ float part[4][16][64];       // 16 KB
        __shared__ float h1s[16][64];           // 4 KB
        int wv = __builtin_amdgcn_readfirstlane(t >> 6);
        int lane = t & 63;
        float w1r[32], w2r[16];
        #pragma unroll
        for (int i = 0; i < 32; ++i) w1r[i] = W1[(wv * 32 + i) * 64 + lane];
        #pragma unroll
        for (int i = 0; i < 16; ++i) w2r[i] = W2[(wv * 16 + i) * 64 + lane];
        float b1v = b1[lane], b2v = b2[lane];
        int srow = t >> 5, sf4 = t & 31;
        float4* st4 = (float4*)stage;

        for (int batch = 0; batch < 4; ++batch) {
            int row0 = tb * 64 + batch * 16;
            #pragma unroll
            for (int p = 0; p < 2; ++p) {
                int row = row0 + srow + 8 * p;
                if (row >= N_NODES) row = N_NODES - 1;
                st4[t + 256 * p] =
                    ((const float4*)(X + (size_t)row * IN_FEATS))[sf4];
            }
            __syncthreads();
            float acc[16];
            #pragma unroll
            for (int r = 0; r < 16; ++r) {
                const float4* xb = (const float4*)&stage[r][wv * 32];
                float a = 0.f, bb = 0.f;
                #pragma unroll
                for (int i4 = 0; i4 < 8; i4 += 2) {
                    float4 v0 = xb[i4], v1 = xb[i4 + 1];
                    a = fmaf(v0.x, w1r[i4 * 4 + 0], a);
                    a = fmaf(v0.y, w1r[i4 * 4 + 1], a);
                    a = fmaf(v0.z, w1r[i4 * 4 + 2], a);
                    a = fmaf(v0.w, w1r[i4 * 4 + 3], a);
                    bb = fmaf(v1.x, w1r[i4 * 4 + 4], bb);
                    bb = fmaf(v1.y, w1r[i4 * 4 + 5], bb);
                    bb = fmaf(v1.z, w1r[i4 * 4 + 6], bb);
                    bb = fmaf(v1.w, w1r[i4 * 4 + 7], bb);
                }
                acc[r] = a + bb;
            }
            #pragma unroll
            for (int r = 0; r < 16; ++r) part[wv][r][lane] = acc[r];
            __syncthreads();
            #pragma unroll
            for (int rr = 0; rr < 4; ++rr) {
                int r = wv * 4 + rr;
                float y1 = part[0][r][lane] + part[1][r][lane] +
                           part[2][r][lane] + part[3][r][lane] + b1v;
                h1s[r][lane] = fmaxf(y1, 0.f);
            }
            __syncthreads();
            float acc2[16];
            #pragma unroll
            for (int r = 0; r < 16; ++r) {
                const float4* xb = (const float4*)&h1s[r][wv * 16];
                float a = 0.f, bb = 0.f;
                #pragma unroll
                for (int i4 = 0; i4 < 4; i4 += 2) {
                    float4 v0 = xb[i4], v1 = xb[i4 + 1];
                    a = fmaf(v0.x, w2r[i4 * 4 + 0], a);
                    a = fmaf(v0.y, w2r[i4 * 4 + 1], a);
                    a = fmaf(v0.z, w2r[i4 * 4 + 2], a);
                    a = fmaf(v0.w, w2r[i4 * 4 + 3], a);
                    bb = fmaf(v1.x, w2r[i4 * 4 + 4], bb);
                    bb = fmaf(v1.y, w2r[i4 * 4 + 5], bb);
                    bb = fmaf(v1.z, w2r[i4 * 4 + 6], bb);
                    bb = fmaf(v1.w, w2r[i4 * 4 + 7], bb);
                }
                acc2[r] = a + bb;
            }
            __syncthreads();
            #pragma unroll
            for (int r = 0; r < 16; ++r) part[wv][r][lane] = acc2[r];
            __syncthreads();
            #pragma unroll
            for (int rr = 0; rr < 4; ++rr) {
                int r = wv * 4 + rr;
                int row = row0 + r;
                float y2 = part[0][r][lane] + part[1][r][lane] +
                           part[2][r][lane] + part[3][r][lane] + b2v;
                if (row < N_NODES) H[(size_t)row * 64 + lane] = __float2half(fmaxf(y2, 0.f));
            }
            __syncthreads();
        }
        return;
    }

    if (b < 2 * NB_TRUNK + (NB_FILL - NB_TRUNK)) {
        // fill role: id in [0, NB_FILL)
        int fid = (b < 2 * NB_TRUNK) ? (b >> 1) : (b - NB_TRUNK);
        int tid = fid * 256 + t;
        const int stride = NB_FILL * 256;
        for (int e = tid; e < N_EDGES; e += stride) {
            int d = dst[e];
            int s = src[e];
            int slot = rowp[d] + atomicAdd(&cursor[d], 1);
            epack[slot] = make_int2(s, __float_as_int(dinv[s]));
        }
        return;
    }

    // wpack role: Weff collapsed + fp16 + MFMA B-fragment order
    // Fragment (s,nt): lane l, elem j holds B[k=32s+(l>>4)*8+j][n=nt*16+(l&15)]
    {
        int wb = b - (2 * NB_TRUNK + (NB_FILL - NB_TRUNK));
        int u = wb * 256 + t;   // 16384 total
        int j = u & 7, lane = (u >> 3) & 63, frag = u >> 9;
        int nt = frag & 3, s = frag >> 2;
        int k = 32 * s + ((lane >> 4) << 3) + j;
        int q = k >> 6, f = k & 63;
        int n = nt * 16 + (lane & 15);
        float acc = 0.f;
        #pragma unroll
        for (int c = 0; c < 3; ++c)
            acc = fmaf(thetas[c * 4 + q], Wm1[(c * 64 + f) * 64 + n], acc);
        Bpack[u] = __float2half(acc);
    }
}

// ---------------- gather pass: Fnew[n] = Fprev[n] - dinv[n]*sum_e w_e*Fprev[s_e]
// half tables (128B row per edge), fp32 accumulate; one wave per node.
__global__ __launch_bounds__(256) void gather_kernel(
    const __half* __restrict__ Fprev, const int* __restrict__ rowp,
    const int2* __restrict__ epack, const float* __restrict__ dinv,
    __half* __restrict__ Fnew)
{
    int wv = __builtin_amdgcn_readfirstlane(threadIdx.x >> 6);
    int wid = blockIdx.x * 4 + wv;   // node id (uniform)
    int lane = threadIdx.x & 63;
    int beg = rowp[wid], end = rowp[wid + 1];
    float acc = 0.0f;
    int j = beg;
    for (; j + 7 < end; j += 8) {
        int2 e0 = epack[j],     e1 = epack[j + 1], e2 = epack[j + 2], e3 = epack[j + 3];
        int2 e4 = epack[j + 4], e5 = epack[j + 5], e6 = epack[j + 6], e7 = epack[j + 7];
        float v0 = __half2float(Fprev[(size_t)e0.x * 64 + lane]);
        float v1 = __half2float(Fprev[(size_t)e1.x * 64 + lane]);
        float v2 = __half2float(Fprev[(size_t)e2.x * 64 + lane]);
        float v3 = __half2float(Fprev[(size_t)e3.x * 64 + lane]);
        float v4 = __half2float(Fprev[(size_t)e4.x * 64 + lane]);
        float v5 = __half2float(Fprev[(size_t)e5.x * 64 + lane]);
        float v6 = __half2float(Fprev[(size_t)e6.x * 64 + lane]);
        float v7 = __half2float(Fprev[(size_t)e7.x * 64 + lane]);
        acc = fmaf(v0, __int_as_float(e0.y), acc);
        acc = fmaf(v1, __int_as_float(e1.y), acc);
        acc = fmaf(v2, __int_as_float(e2.y), acc);
        acc = fmaf(v3, __int_as_float(e3.y), acc);
        acc = fmaf(v4, __int_as_float(e4.y), acc);
        acc = fmaf(v5, __int_as_float(e5.y), acc);
        acc = fmaf(v6, __int_as_float(e6.y), acc);
        acc = fmaf(v7, __int_as_float(e7.y), acc);
    }
    for (; j < end; ++j) {
        int2 e = epack[j];
        acc = fmaf(__half2float(Fprev[(size_t)e.x * 64 + lane]), __int_as_float(e.y), acc);
    }
    float self = __half2float(Fprev[(size_t)wid * 64 + lane]);
    Fnew[(size_t)wid * 64 + lane] = __float2half(self - acc * dinv[wid]);
}

// ---------------- final (MFMA): out = relu(A@B + bm1) @ Wm2 + bm2 ----------------
// A[100000 x 256] fp16 = [L0|L1|L2|L3] column-blocked (Lh contiguous);
// B[256 x 64] fp16 pre-packed in fragment order (Bpack).
// D: col n = nt*16 + (l&15), row = row0 + (l>>4)*4 + reg   [m89 layout]
__global__ __launch_bounds__(256) void final_mfma_kernel(
    const __half* __restrict__ L0h, const __half* __restrict__ Bpack,
    const float* __restrict__ Wm2, const float* __restrict__ bm1,
    const float* __restrict__ bm2, float* __restrict__ out)
{
    const size_t NH = (size_t)N_NODES * 64;
    int t = threadIdx.x;
    int wv = t >> 6;
    int lane = t & 63;
    int gw = blockIdx.x * 4 + wv;          // 1564 waves

    // preload all 32 B fragments (128 VGPRs)
    const f16x8* bp = (const f16x8*)Bpack;
    f16x8 b[4][8];
    #pragma unroll
    for (int s = 0; s < 8; ++s)
        #pragma unroll
        for (int nt = 0; nt < 4; ++nt)
            b[nt][s] = bp[(s * 4 + nt) * 64 + lane];

    // per-lane head constants: n = nt*16 + (lane&15)
    float bm1v[4], w20[4], w21[4];
    #pragma unroll
    for (int nt = 0; nt < 4; ++nt) {
        int n = nt * 16 + (lane & 15);
        bm1v[nt] = bm1[n];
        w20[nt] = Wm2[n * 2 + 0];
        w21[nt] = Wm2[n * 2 + 1];
    }
    float bm20 = bm2[0], bm21 = bm2[1];

    for (int u = 0; u < 4; ++u) {
        int tile = gw * 4 + u;
        if (tile >= 6250) break;           // 6250 * 16 = 100000 exactly
        int row0 = tile * 16;
        const __half* abase = L0h + (size_t)(row0 + (lane & 15)) * 64 + ((lane >> 4) << 3);
        f16x8 a[8];
        #pragma unroll
        for (int s = 0; s < 8; ++s)
            a[s] = *(const f16x8*)(abase + (size_t)(s >> 1) * NH + 32 * (s & 1));
        f32x4 acc[4];
        #pragma unroll
        for (int nt = 0; nt < 4; ++nt) acc[nt] = (f32x4){0.f, 0.f, 0.f, 0.f};
        #pragma unroll
        for (int s = 0; s < 8; ++s)
            #pragma unroll
            for (int nt = 0; nt < 4; ++nt)
                acc[nt] = __builtin_amdgcn_mfma_f32_16x16x32_f16(a[s], b[nt][s], acc[nt], 0, 0, 0);
        // epilogue: relu + bm1, head GEMV, reduce over n within 16-lane groups
        float o0[4], o1[4];
        #pragma unroll
        for (int reg = 0; reg < 4; ++reg) { o0[reg] = 0.f; o1[reg] = 0.f; }
        #pragma unroll
        for (int nt = 0; nt < 4; ++nt)
            #pragma unroll
            for (int reg = 0; reg < 4; ++reg) {
                float v = fmaxf(acc[nt][reg] + bm1v[nt], 0.f);
                o0[reg] = fmaf(v, w20[nt], o0[reg]);
                o1[reg] = fmaf(v, w21[nt], o1[reg]);
            }
        #pragma unroll
        for (int reg = 0; reg < 4; ++reg) {
            #pragma unroll
            for (int m = 8; m > 0; m >>= 1) {
                o0[reg] += __shfl_xor(o0[reg], m);
                o1[reg] += __shfl_xor(o1[reg], m);
            }
        }
        if ((lane & 15) == 0) {
            int rbase = row0 + (lane >> 4) * 4;
            #pragma unroll
            for (int reg = 0; reg < 4; ++reg) {
                out[(rbase + reg) * 2 + 0] = o0[reg] + bm20;
                out[(rbase + reg) * 2 + 1] = o1[reg] + bm21;
            }
        }
    }
}

extern "C" void kernel_launch(void* const* d_in, const int* in_sizes, int n_in,
                              void* d_out, int out_size, void* d_ws, size_t ws_size,
                              hipStream_t stream)
{
    const float* feature = (const float*)d_in[0];
    const int*   src     = (const int*)d_in[1];
    const int*   dst     = (const int*)d_in[2];
    const float* W1      = (const float*)d_in[3];
    const float* b1      = (const float*)d_in[4];
    const float* W2      = (const float*)d_in[5];
    const float* b2      = (const float*)d_in[6];
    const float* thetas  = (const float*)d_in[7];
    const float* Wm1     = (const float*)d_in[8];
    const float* bm1     = (const float*)d_in[9];
    const float* Wm2     = (const float*)d_in[10];
    const float* bm2     = (const float*)d_in[11];
    float* out = (float*)d_out;

    const size_t NH = (size_t)N_NODES * H_FEATS;   // 6.4M elems
    const int NPAD = 100352;
    float*  dinv   = (float*)d_ws;                  // N
    int*    degi   = (int*)(dinv + NPAD);           // N
    int*    rowp   = degi + NPAD;                   // N+1
    int*    bsums  = rowp + NPAD;                   // 512
    int*    cursor = bsums + 512;                   // N
    int2*   epack  = (int2*)(cursor + NPAD);        // E int2
    __half* Lh     = (__half*)(epack + N_EDGES);    // 4 x NH halfs, contiguous
    __half* Bpack  = Lh + 4 * NH;                   // 16384 halfs (32 KB)
    // total ws use ≈ 66 MB

    hipMemsetAsync(degi,   0, N_NODES * sizeof(int), stream);
    hipMemsetAsync(cursor, 0, N_NODES * sizeof(int), stream);

    hist_kernel<<<1024, 256, 0, stream>>>(dst, degi);
    scan1_kernel<<<SCAN_BLOCKS, 256, 0, stream>>>(degi, rowp, bsums, dinv);
    scan2_kernel<<<1, 512, 0, stream>>>(bsums);
    scan3_kernel<<<SCAN_BLOCKS, 256, 0, stream>>>(rowp, bsums);

    mega_kernel<<<NB_MEGA, 256, 0, stream>>>(
        feature, W1, b1, W2, b2, Lh,
        src, dst, rowp, dinv, cursor, epack,
        thetas, Wm1, Bpack);

    for (int k = 1; k <= 3; ++k)
        gather_kernel<<<25000, 256, 0, stream>>>(Lh + (size_t)(k - 1) * NH, rowp, epack,
                                                 dinv, Lh + (size_t)k * NH);

    final_mfma_kernel<<<391, 256, 0, stream>>>(Lh, Bpack, Wm2, bm1, bm2, out);
}